// Round 16
// baseline (99.183 us; speedup 1.0000x reference)
//
#include <hip/hip_runtime.h>
#include <hip/hip_bf16.h>
#include <stdint.h>

#define NG 512            // graphs
#define NN 39             // nodes per graph
#define FIN0 39           // input features
#define HID 256
#define KNN 10
#define NROWS (NG * NN)   // 19968
#define BNEPS 1e-5f

typedef __hip_bfloat16 bf16;
typedef __attribute__((ext_vector_type(8))) short s16x8;
typedef __attribute__((ext_vector_type(4))) float f32x4;

__device__ __forceinline__ void split_bf16(float v, bf16& hi, bf16& lo) {
  hi = __float2bfloat16(v);
  lo = __float2bfloat16(v - __bfloat162float(hi));
}

// asm-pinned 16B global loads (scheduler cannot re-glue load->use; R5-R7 lesson)
__device__ __forceinline__ void ld_b128(s16x8& d, const bf16* base, unsigned voff) {
  asm volatile("global_load_dwordx4 %0, %1, %2" : "=v"(d) : "v"(voff), "s"(base));
}
__device__ __forceinline__ void ld_f32x4(f32x4& d, const float* base, unsigned voff) {
  asm volatile("global_load_dwordx4 %0, %1, %2" : "=v"(d) : "v"(voff), "s"(base));
}
#define WAITV4 do { asm volatile("s_waitcnt vmcnt(4)"); __builtin_amdgcn_sched_barrier(0); } while (0)
#define WAITV0 do { asm volatile("s_waitcnt vmcnt(0)"); __builtin_amdgcn_sched_barrier(0); } while (0)

// ---------------------------------------------------------------------------
// prep: W*T in FRAGMENT ORDER with column interleave (c = (cb/4)*64 + 4*fr +
// (cb&3); k = ks*32 + fq*8 + e).  Tiled (R11 version, bit-identical output):
// one block per (W, colblock, ks) -> coalesced row-segment loads, fold in
// LDS, fragment-order emit.
//   blocks 0..15  : W1 (colblock 0..7 x ks 0..1)
//   blocks 16..79 : W2; blocks 80..143: W3
// ---------------------------------------------------------------------------
__global__ __launch_bounds__(256) void k_prepw(const float* __restrict__ W1,
                                               const float* __restrict__ W2,
                                               const float* __restrict__ W3,
                                               bf16* __restrict__ W1Th, bf16* __restrict__ W1Tl,
                                               bf16* __restrict__ W2Th, bf16* __restrict__ W2Tl,
                                               bf16* __restrict__ W3Th, bf16* __restrict__ W3Tl) {
  __shared__ float tile[32][65];
  const int blk = blockIdx.x, tid = threadIdx.x;
  const float* W; bf16 *Th, *Tl; int NKS_, F, colblock, ks;
  if (blk < 16)      { W = W1; Th = W1Th; Tl = W1Tl; NKS_ = 2; F = FIN0; colblock = blk >> 1;        ks = blk & 1; }
  else if (blk < 80) { W = W2; Th = W2Th; Tl = W2Tl; NKS_ = 8; F = HID;  colblock = (blk - 16) >> 3; ks = (blk - 16) & 7; }
  else               { W = W3; Th = W3Th; Tl = W3Tl; NKS_ = 8; F = HID;  colblock = (blk - 80) >> 3; ks = (blk - 80) & 7; }

  // load + fold [32k x 64c] tile, coalesced 32B row segments per thread
  const int kl = tid >> 3, cseg = (tid & 7) * 8;
  const int k = ks * 32 + kl;
  const int cg = colblock * 64 + cseg;
  float v[8];
  if (k < F) {
    if (colblock < 4) {
#pragma unroll
      for (int j = 0; j < 8; j++) v[j] = W[k * HID + cg + j] - W[(F + k) * HID + cg + j];
    } else {
#pragma unroll
      for (int j = 0; j < 8; j++) v[j] = W[(F + k) * HID + (cg - 256) + j];
    }
  } else {
#pragma unroll
    for (int j = 0; j < 8; j++) v[j] = 0.f;
  }
#pragma unroll
  for (int j = 0; j < 8; j++) tile[kl][cseg + j] = v[j];
  __syncthreads();

  // emit: thread = (q, li); frag = (colblock*4+q)*NKS + ks; elem = li*8+e
  const int q = tid >> 6, li = tid & 63, fr = li & 15, fq = li >> 4;
  const int cl = 4 * fr + q;
  union { bf16 b8[8]; s16x8 s; } hh, ll;
#pragma unroll
  for (int e = 0; e < 8; e++) split_bf16(tile[fq * 8 + e][cl], hh.b8[e], ll.b8[e]);
  const size_t frag = (size_t)((colblock * 4 + q) * NKS_ + ks);
  *(s16x8*)(Th + frag * 512 + li * 8) = hh.s;
  *(s16x8*)(Tl + frag * 512 + li * 8) = ll.s;
}

// ---------------------------------------------------------------------------
// Fused layer kernel (R9/R13/R15 byte-identical): one block (512 thr)/graph.
// EXACTLY TWO instantiations (<64,true>, <256,false>) -- a third regressed
// graph-warm perf by +50% with identical rocprof counters (R14 bisect).
// ---------------------------------------------------------------------------
#define VSTR 260
#define RSTR 260
template <int K, bool FIRST>   // <64,true> (layer1) or <256,false> (layers 2/3)
__global__ __launch_bounds__(512, 4) void k_fused(const float* __restrict__ fin,
                                                  const float* __restrict__ st,
                                                  const bf16* __restrict__ BTh,
                                                  const bf16* __restrict__ BTl,
                                                  const float* __restrict__ bias,
                                                  float* __restrict__ h_out,
                                                  float* __restrict__ part) {
  constexpr int XBYTES = 48 * K * 2 * 2;            // Xh+Xl
  constexpr int ALIAS = (NN * VSTR + 8 * RSTR) * 4; // vsh + red
  constexpr int SBASE = (XBYTES > ALIAS) ? XBYTES : ((ALIAS + 15) & ~15);
  __shared__ __align__(16) char smem[SBASE + 6240 + 160 + 1568];
  bf16* Xh = (bf16*)smem;                  // [48][K]
  bf16* Xl = Xh + 48 * K;                  // [48][K]
  float* vsh = (float*)smem;               // [39][VSTR]  (phase>=4, X dead)
  float* red = (float*)(smem + NN * VSTR * 4);      // [8][RSTR] (phase 5)
  float* dmat = (float*)(smem + SBASE);    // [39][40]
  float* sqv  = (float*)(smem + SBASE + 6240);      // [39]
  int*   idxs = (int*)(smem + SBASE + 6240 + 160);  // [39][10]

  const int b = blockIdx.x, tid = threadIdx.x;
  const int wv = tid >> 6, ln = tid & 63;
  const int fr = ln & 15, fq = ln >> 4;
  const size_t base = (size_t)b * NN;
  constexpr int NKS = K / 32;

  // ---- p0: pipelined load + (BN+relu) + split + swizzled ds_write_b128 ----
  if (FIRST) {
    if (tid < 48 * 8) {
      const int row = tid >> 3, g = tid & 7;
      union { bf16 b8[8]; s16x8 v; } ph, pl;
      if (row < NN) {
#pragma unroll
        for (int j = 0; j < 8; j++) {
          const int k = g * 8 + j;
          const float x = (k < FIN0) ? fin[(base + row) * FIN0 + k] : 0.f;
          split_bf16(x, ph.b8[j], pl.b8[j]);
        }
      } else {
#pragma unroll
        for (int j = 0; j < 8; j++) { ph.b8[j] = __float2bfloat16(0.f); pl.b8[j] = ph.b8[j]; }
      }
      const int ad = row * K + ((g ^ (row & 7)) << 3);
      *(s16x8*)&Xh[ad] = ph.v;
      *(s16x8*)&Xl[ad] = pl.v;
    }
  } else {
    // K=256: exactly 3 granule16/thread (rows r0, r0+16, r0+32), same g.
    const int r0 = tid >> 5, g = tid & 31;
    const unsigned o0 = (unsigned)((((base + r0) * HID) + g * 8) * 4);
    const unsigned rstep = (unsigned)(16 * HID * 4);
    f32x4 a0, a1, b0, b1, c0v, c1v;
    ld_f32x4(a0, fin, o0);             ld_f32x4(a1, fin, o0 + 16);
    ld_f32x4(b0, fin, o0 + rstep);     ld_f32x4(b1, fin, o0 + rstep + 16);
    ld_f32x4(c0v, fin, o0 + 2 * rstep); ld_f32x4(c1v, fin, o0 + 2 * rstep + 16);
    // BN scale/shift for this thread's 8 channels (same for all 3 rows)
    const f32x4 sc0 = *(const f32x4*)&st[g * 8];
    const f32x4 sc1 = *(const f32x4*)&st[g * 8 + 4];
    const f32x4 sh0 = *(const f32x4*)&st[HID + g * 8];
    const f32x4 sh1 = *(const f32x4*)&st[HID + g * 8 + 4];
    WAITV0;
    auto proc = [&](int row, const f32x4& lo4, const f32x4& hi4) {
      union { bf16 b8[8]; s16x8 v; } ph, pl;
#pragma unroll
      for (int j = 0; j < 4; j++) {
        const float v = fmaxf(lo4[j] * sc0[j] + sh0[j], 0.f);
        split_bf16(v, ph.b8[j], pl.b8[j]);
      }
#pragma unroll
      for (int j = 0; j < 4; j++) {
        const float v = fmaxf(hi4[j] * sc1[j] + sh1[j], 0.f);
        split_bf16(v, ph.b8[4 + j], pl.b8[4 + j]);
      }
      const int ad = row * K + ((g ^ (row & 7)) << 3);
      *(s16x8*)&Xh[ad] = ph.v;
      *(s16x8*)&Xl[ad] = pl.v;
    };
    proc(r0, a0, a1);
    proc(r0 + 16, b0, b1);
    const int r2 = r0 + 32;
    if (r2 < NN) proc(r2, c0v, c1v);
    else {                              // pad rows 39..47: zeros
      union { bf16 b8[8]; s16x8 v; } z;
#pragma unroll
      for (int j = 0; j < 8; j++) z.b8[j] = __float2bfloat16(0.f);
      const int ad = r2 * K + ((g ^ (r2 & 7)) << 3);
      *(s16x8*)&Xh[ad] = z.v;
      *(s16x8*)&Xl[ad] = z.v;
    }
  }

  // pre-issue p4's B H(0) fragment loads; the barrier's vmcnt drain lands them
  unsigned fb[4];
#pragma unroll
  for (int n = 0; n < 4; n++)
    fb[n] = ((unsigned)((wv * 4 + n) * NKS) << 10) + (unsigned)(ln * 16);
  s16x8 bufH[4], bufL[4];
#pragma unroll
  for (int n = 0; n < 4; n++) ld_b128(bufH[n], BTh, fb[n]);
  __syncthreads();

  // ---- p1: Gram via MFMA (9 16x16 tile-pairs over 8 waves) ----
  for (int p = wv; p < 9; p += 8) {
    const int mi = p / 3, ni = p % 3;
    f32x4 acg = (f32x4){0.f, 0.f, 0.f, 0.f};
    const int ar = mi * 16 + fr, br = ni * 16 + fr;
#pragma unroll
    for (int ks = 0; ks < NKS; ks++) {
      const int ga = ((ks * 4 + fq) ^ (ar & 7)) << 3;
      const int gb = ((ks * 4 + fq) ^ (br & 7)) << 3;
      const s16x8 avh = *(const s16x8*)&Xh[ar * K + ga];
      const s16x8 avl = *(const s16x8*)&Xl[ar * K + ga];
      const s16x8 bvh = *(const s16x8*)&Xh[br * K + gb];
      const s16x8 bvl = *(const s16x8*)&Xl[br * K + gb];
      acg = __builtin_amdgcn_mfma_f32_16x16x32_bf16(avh, bvh, acg, 0, 0, 0);
      acg = __builtin_amdgcn_mfma_f32_16x16x32_bf16(avh, bvl, acg, 0, 0, 0);
      acg = __builtin_amdgcn_mfma_f32_16x16x32_bf16(avl, bvh, acg, 0, 0, 0);
    }
    const int oc = ni * 16 + fr;           // C layout: col=lane&15
    if (oc < NN) {
#pragma unroll
      for (int r = 0; r < 4; r++) {        // row=(lane>>4)*4+reg
        const int orow = mi * 16 + fq * 4 + r;
        if (orow < NN) dmat[orow * 40 + oc] = acg[r];
      }
    }
  }
  __syncthreads();

  // ---- p2: distances in place ----
  if (tid < NN) sqv[tid] = dmat[tid * 40 + tid];
  __syncthreads();
  for (int t = tid; t < NN * NN; t += 512) {
    const int i = t / NN, j = t - i * NN;
    dmat[i * 40 + j] = sqv[i] + sqv[j] - 2.f * dmat[i * 40 + j];
  }
  __syncthreads();

  // ---- p3: top-10 per row, 4-lane groups (stable tie-break = lax.top_k) ----
  const int grp = tid >> 2, l4 = tid & 3;
  if (grp < NN) {
    float dv[10];
#pragma unroll
    for (int s = 0; s < 10; s++) {
      const int j = l4 + s * 4;
      dv[s] = (j < NN) ? dmat[grp * 40 + j] : 3.4e38f;
    }
    unsigned taken = 0;
    for (int k = 0; k < KNN; k++) {
      float bv = 3.4e38f;
      int bi = 1 << 30;
#pragma unroll
      for (int s = 0; s < 10; s++) {
        const float v = ((taken >> s) & 1u) ? 3.4e38f : dv[s];
        const int j = l4 + s * 4;
        if (v < bv || (v == bv && j < bi)) { bv = v; bi = j; }
      }
#pragma unroll
      for (int m = 1; m < 4; m <<= 1) {
        const float ov = __shfl_xor(bv, m, 64);
        const int oi = __shfl_xor(bi, m, 64);
        if (ov < bv || (ov == bv && oi < bi)) { bv = ov; bi = oi; }
      }
      if ((bi & 3) == l4) taken |= 1u << (bi >> 2);
      if (l4 == 0) idxs[grp * 10 + k] = bi;
    }
  }

  // ---- p4: GEMM. wave wv owns cols [wv*64, wv*64+64); frag n = channels
  //      wcol0 + 4*fr + n. H(0) already resident (pre-barrier issue). ----
  f32x4 acc[3][4];
#pragma unroll
  for (int m = 0; m < 3; m++)
#pragma unroll
    for (int n = 0; n < 4; n++) acc[m][n] = (f32x4){0.f, 0.f, 0.f, 0.f};

#pragma unroll
  for (int ks = 0; ks < NKS; ks++) {
#pragma unroll
    for (int n = 0; n < 4; n++) ld_b128(bufL[n], BTl, fb[n] + (unsigned)ks * 1024);
    s16x8 ah0, ah1, ah2, al0, al1, al2;   // A-fragments once per ks
    {
      const int r0w = fr, r1w = 16 + fr, r2w = 32 + fr;
      const int g0 = ((ks * 4 + fq) ^ (r0w & 7)) << 3;
      const int g1 = ((ks * 4 + fq) ^ (r1w & 7)) << 3;
      const int g2 = ((ks * 4 + fq) ^ (r2w & 7)) << 3;
      ah0 = *(const s16x8*)&Xh[r0w * K + g0]; al0 = *(const s16x8*)&Xl[r0w * K + g0];
      ah1 = *(const s16x8*)&Xh[r1w * K + g1]; al1 = *(const s16x8*)&Xl[r1w * K + g1];
      ah2 = *(const s16x8*)&Xh[r2w * K + g2]; al2 = *(const s16x8*)&Xl[r2w * K + g2];
    }
    WAITV4;                          // H(ks) landed; L(ks) in flight
#pragma unroll
    for (int n = 0; n < 4; n++) {    // hh + lh products (24 MFMA)
      acc[0][n] = __builtin_amdgcn_mfma_f32_16x16x32_bf16(ah0, bufH[n], acc[0][n], 0, 0, 0);
      acc[0][n] = __builtin_amdgcn_mfma_f32_16x16x32_bf16(al0, bufH[n], acc[0][n], 0, 0, 0);
      acc[1][n] = __builtin_amdgcn_mfma_f32_16x16x32_bf16(ah1, bufH[n], acc[1][n], 0, 0, 0);
      acc[1][n] = __builtin_amdgcn_mfma_f32_16x16x32_bf16(al1, bufH[n], acc[1][n], 0, 0, 0);
      acc[2][n] = __builtin_amdgcn_mfma_f32_16x16x32_bf16(ah2, bufH[n], acc[2][n], 0, 0, 0);
      acc[2][n] = __builtin_amdgcn_mfma_f32_16x16x32_bf16(al2, bufH[n], acc[2][n], 0, 0, 0);
    }
    if (ks + 1 < NKS) {
#pragma unroll
      for (int n = 0; n < 4; n++) ld_b128(bufH[n], BTh, fb[n] + (unsigned)(ks + 1) * 1024);
      WAITV4;                        // L(ks) landed; H(ks+1) in flight
    } else {
      WAITV0;                        // L(last) landed
    }
#pragma unroll
    for (int n = 0; n < 4; n++) {    // hl products (12 MFMA)
      acc[0][n] = __builtin_amdgcn_mfma_f32_16x16x32_bf16(ah0, bufL[n], acc[0][n], 0, 0, 0);
      acc[1][n] = __builtin_amdgcn_mfma_f32_16x16x32_bf16(ah1, bufL[n], acc[1][n], 0, 0, 0);
      acc[2][n] = __builtin_amdgcn_mfma_f32_16x16x32_bf16(ah2, bufL[n], acc[2][n], 0, 0, 0);
    }
  }
  __syncthreads();   // all X-reads done; X region may be overwritten (vsh)

  if (wv >= 4) {     // v-waves: acc -> vsh[row][c0..c0+3] (f32x4 stores)
    const int c0 = (wv - 4) * 64 + fr * 4;
#pragma unroll
    for (int m = 0; m < 3; m++)
#pragma unroll
      for (int r = 0; r < 4; r++) {
        const int row = m * 16 + fq * 4 + r;
        if (row < NN) {
          const f32x4 v4 = (f32x4){acc[m][0][r], acc[m][1][r], acc[m][2][r], acc[m][3][r]};
          *(f32x4*)&vsh[row * VSTR + c0] = v4;
        }
      }
  } else {           // u-waves: add bias (channel c0+n per acc slot n)
    const int c0 = wv * 64 + fr * 4;
    const f32x4 bv = *(const f32x4*)&bias[c0];
#pragma unroll
    for (int n = 0; n < 4; n++)
#pragma unroll
      for (int m = 0; m < 3; m++)
#pragma unroll
        for (int r = 0; r < 4; r++) acc[m][n][r] += bv[n];
  }
  __syncthreads();   // vsh + idxs ready

  // ---- p5: h = relu(u + max_k v); f32x4 LDS reads; BN partials ----
  if (wv < 4) {
    const int c0 = wv * 64 + fr * 4;
    f32x4 s1 = (f32x4){0.f, 0.f, 0.f, 0.f}, s2 = (f32x4){0.f, 0.f, 0.f, 0.f};
#pragma unroll
    for (int m = 0; m < 3; m++)
#pragma unroll
      for (int r = 0; r < 4; r++) {
        const int row = m * 16 + fq * 4 + r;
        if (row < NN) {
          int nb[10];
#pragma unroll
          for (int k = 0; k < KNN; k++) nb[k] = idxs[row * 10 + k];
          f32x4 vm = (f32x4){-3.4e38f, -3.4e38f, -3.4e38f, -3.4e38f};
#pragma unroll
          for (int k = 0; k < KNN; k++) {
            const f32x4 t4 = *(const f32x4*)&vsh[nb[k] * VSTR + c0];
            vm[0] = fmaxf(vm[0], t4[0]); vm[1] = fmaxf(vm[1], t4[1]);
            vm[2] = fmaxf(vm[2], t4[2]); vm[3] = fmaxf(vm[3], t4[3]);
          }
          f32x4 h4;
#pragma unroll
          for (int j = 0; j < 4; j++) h4[j] = fmaxf(acc[m][j][r] + vm[j], 0.f);
          *(f32x4*)&h_out[(size_t)(base + row) * HID + c0] = h4;
#pragma unroll
          for (int j = 0; j < 4; j++) { s1[j] += h4[j]; s2[j] += h4[j] * h4[j]; }
        }
      }
    *(f32x4*)&red[fq * RSTR + c0] = s1;
    *(f32x4*)&red[(4 + fq) * RSTR + c0] = s2;
  }
  __syncthreads();
  if (tid < HID) {
    part[(size_t)b * 512 + tid] =
        red[0 * RSTR + tid] + red[1 * RSTR + tid] + red[2 * RSTR + tid] + red[3 * RSTR + tid];
    part[(size_t)b * 512 + HID + tid] =
        red[4 * RSTR + tid] + red[5 * RSTR + tid] + red[6 * RSTR + tid] + red[7 * RSTR + tid];
  }
}

// stats reduce: one block per channel; deterministic tree order.
__global__ __launch_bounds__(256) void k_stats(const float* __restrict__ part,
                                               const float* __restrict__ gam,
                                               const float* __restrict__ bet,
                                               float* __restrict__ st) {
  __shared__ float rs[4], rq[4];
  const int c = blockIdx.x, tid = threadIdx.x;
  float s = part[(size_t)tid * 512 + c] + part[(size_t)(tid + 256) * 512 + c];
  float q = part[(size_t)tid * 512 + HID + c] + part[(size_t)(tid + 256) * 512 + HID + c];
#pragma unroll
  for (int m = 32; m >= 1; m >>= 1) { s += __shfl_down(s, m, 64); q += __shfl_down(q, m, 64); }
  if ((tid & 63) == 0) { rs[tid >> 6] = s; rq[tid >> 6] = q; }
  __syncthreads();
  if (tid == 0) {
    s = rs[0] + rs[1] + rs[2] + rs[3];
    q = rq[0] + rq[1] + rq[2] + rq[3];
    const float mean = s * (1.f / NROWS);
    const float var = q * (1.f / NROWS) - mean * mean;
    const float sc = gam[c] * rsqrtf(var + BNEPS);
    st[c] = sc;
    st[HID + c] = bet[c] - mean * sc;
  }
}

// final: pooled = BN(part_sum/NN); logits; softmax.  part[b*512+c] is the
// channel-sum of h3 over graph b's 39 rows (computed by layer-3's p5) --
// h3 itself is still stored (dead) to keep k_fused byte-identical.
__global__ __launch_bounds__(256) void k_final(const float* __restrict__ part,
                                               const float* __restrict__ st,
                                               const float* __restrict__ Wl,
                                               const float* __restrict__ bl,
                                               float* __restrict__ out) {
  __shared__ float r0[HID], r1[HID];
  const int b = blockIdx.x, c = threadIdx.x;
  const float s = part[(size_t)b * 512 + c];
  const float pooled = (s * (1.f / NN)) * st[c] + st[HID + c];
  r0[c] = pooled * Wl[c * 2 + 0];
  r1[c] = pooled * Wl[c * 2 + 1];
  __syncthreads();
  for (int stp = 128; stp > 0; stp >>= 1) {
    if (c < stp) { r0[c] += r0[c + stp]; r1[c] += r1[c + stp]; }
    __syncthreads();
  }
  if (c == 0) {
    const float l0 = r0[0] + bl[0], l1 = r1[0] + bl[1];
    const float mx = fmaxf(l0, l1);
    const float e0 = expf(l0 - mx), e1 = expf(l1 - mx);
    const float inv = 1.f / (e0 + e1);
    out[b * 2 + 0] = e0 * inv;
    out[b * 2 + 1] = e1 * inv;
  }
}

extern "C" void kernel_launch(void* const* d_in, const int* in_sizes, int n_in,
                              void* d_out, int out_size, void* d_ws, size_t ws_size,
                              hipStream_t stream) {
  const float* x   = (const float*)d_in[0];
  // d_in[1] = batch (structure fixed: repeat(arange(512), 39)) -- unused
  const float* W1  = (const float*)d_in[2];
  const float* b1  = (const float*)d_in[3];
  const float* W2  = (const float*)d_in[4];
  const float* b2  = (const float*)d_in[5];
  const float* W3  = (const float*)d_in[6];
  const float* b3  = (const float*)d_in[7];
  const float* g1  = (const float*)d_in[8];
  const float* be1 = (const float*)d_in[9];
  const float* g2  = (const float*)d_in[10];
  const float* be2 = (const float*)d_in[11];
  const float* g3  = (const float*)d_in[12];
  const float* be3 = (const float*)d_in[13];
  const float* Wl  = (const float*)d_in[14];
  const float* bl  = (const float*)d_in[15];

  char* ws = (char*)d_ws;
  size_t off = 0;
  auto alloc = [&](size_t bytes) {
    size_t o = off;
    off += (bytes + 255) & ~(size_t)255;
    return o;
  };
  bf16* W1Th = (bf16*)(ws + alloc(512 * 64 * 2));
  bf16* W1Tl = (bf16*)(ws + alloc(512 * 64 * 2));
  bf16* W2Th = (bf16*)(ws + alloc(512 * 256 * 2));
  bf16* W2Tl = (bf16*)(ws + alloc(512 * 256 * 2));
  bf16* W3Th = (bf16*)(ws + alloc(512 * 256 * 2));
  bf16* W3Tl = (bf16*)(ws + alloc(512 * 256 * 2));
  float* hA  = (float*)(ws + alloc((size_t)NROWS * HID * 4));
  float* hB  = (float*)(ws + alloc((size_t)NROWS * HID * 4));
  float* part = (float*)(ws + alloc((size_t)NG * 512 * 4));
  float* st1 = (float*)(ws + alloc(512 * 4));
  float* st2 = (float*)(ws + alloc(512 * 4));
  float* st3 = (float*)(ws + alloc(512 * 4));
  if (off > ws_size) return;  // workspace too small -> visible failure

  k_prepw<<<144, 256, 0, stream>>>(W1, W2, W3, W1Th, W1Tl, W2Th, W2Tl, W3Th, W3Tl);

  // layer 1 (raw x input, no BN on load)
  k_fused<64, true><<<NG, 512, 0, stream>>>(x, nullptr, W1Th, W1Tl, b1, hA, part);
  k_stats<<<HID, 256, 0, stream>>>(part, g1, be1, st1);

  // layer 2 (BN+relu of hA applied on load)
  k_fused<256, false><<<NG, 512, 0, stream>>>(hA, st1, W2Th, W2Tl, b2, hB, part);
  k_stats<<<HID, 256, 0, stream>>>(part, g2, be2, st2);

  // layer 3 (same instantiation as layer 2; hA store kept to preserve codegen)
  k_fused<256, false><<<NG, 512, 0, stream>>>(hB, st2, W3Th, W3Tl, b3, hA, part);
  k_stats<<<HID, 256, 0, stream>>>(part, g3, be3, st3);

  // pool (from part, 1 MB) + linear + softmax
  k_final<<<NG, 256, 0, stream>>>(part, st3, Wl, bl, (float*)d_out);
}

// Round 17
// 97.896 us; speedup vs baseline: 1.0131x; 1.0131x over previous
//
#include <hip/hip_runtime.h>
#include <hip/hip_bf16.h>
#include <stdint.h>

#define NG 512            // graphs
#define NN 39             // nodes per graph
#define FIN0 39           // input features
#define HID 256
#define KNN 10
#define NROWS (NG * NN)   // 19968
#define BNEPS 1e-5f

typedef __hip_bfloat16 bf16;
typedef __attribute__((ext_vector_type(8))) short s16x8;
typedef __attribute__((ext_vector_type(4))) float f32x4;

__device__ __forceinline__ void split_bf16(float v, bf16& hi, bf16& lo) {
  hi = __float2bfloat16(v);
  lo = __float2bfloat16(v - __bfloat162float(hi));
}

// asm-pinned 16B global loads (scheduler cannot re-glue load->use; R5-R7 lesson)
__device__ __forceinline__ void ld_b128(s16x8& d, const bf16* base, unsigned voff) {
  asm volatile("global_load_dwordx4 %0, %1, %2" : "=v"(d) : "v"(voff), "s"(base));
}
__device__ __forceinline__ void ld_f32x4(f32x4& d, const float* base, unsigned voff) {
  asm volatile("global_load_dwordx4 %0, %1, %2" : "=v"(d) : "v"(voff), "s"(base));
}
#define WAITV4 do { asm volatile("s_waitcnt vmcnt(4)"); __builtin_amdgcn_sched_barrier(0); } while (0)
#define WAITV0 do { asm volatile("s_waitcnt vmcnt(0)"); __builtin_amdgcn_sched_barrier(0); } while (0)

// ---------------------------------------------------------------------------
// prep: W*T in FRAGMENT ORDER with column interleave (c = (cb/4)*64 + 4*fr +
// (cb&3); k = ks*32 + fq*8 + e).  Tiled: one block per (W, colblock, ks) ->
// coalesced row-segment loads, fold in LDS, fragment-order emit.
// ---------------------------------------------------------------------------
__global__ __launch_bounds__(256) void k_prepw(const float* __restrict__ W1,
                                               const float* __restrict__ W2,
                                               const float* __restrict__ W3,
                                               bf16* __restrict__ W1Th, bf16* __restrict__ W1Tl,
                                               bf16* __restrict__ W2Th, bf16* __restrict__ W2Tl,
                                               bf16* __restrict__ W3Th, bf16* __restrict__ W3Tl) {
  __shared__ float tile[32][65];
  const int blk = blockIdx.x, tid = threadIdx.x;
  const float* W; bf16 *Th, *Tl; int NKS_, F, colblock, ks;
  if (blk < 16)      { W = W1; Th = W1Th; Tl = W1Tl; NKS_ = 2; F = FIN0; colblock = blk >> 1;        ks = blk & 1; }
  else if (blk < 80) { W = W2; Th = W2Th; Tl = W2Tl; NKS_ = 8; F = HID;  colblock = (blk - 16) >> 3; ks = (blk - 16) & 7; }
  else               { W = W3; Th = W3Th; Tl = W3Tl; NKS_ = 8; F = HID;  colblock = (blk - 80) >> 3; ks = (blk - 80) & 7; }

  // load + fold [32k x 64c] tile, coalesced 32B row segments per thread
  const int kl = tid >> 3, cseg = (tid & 7) * 8;
  const int k = ks * 32 + kl;
  const int cg = colblock * 64 + cseg;
  float v[8];
  if (k < F) {
    if (colblock < 4) {
#pragma unroll
      for (int j = 0; j < 8; j++) v[j] = W[k * HID + cg + j] - W[(F + k) * HID + cg + j];
    } else {
#pragma unroll
      for (int j = 0; j < 8; j++) v[j] = W[(F + k) * HID + (cg - 256) + j];
    }
  } else {
#pragma unroll
    for (int j = 0; j < 8; j++) v[j] = 0.f;
  }
#pragma unroll
  for (int j = 0; j < 8; j++) tile[kl][cseg + j] = v[j];
  __syncthreads();

  // emit: thread = (q, li); frag = (colblock*4+q)*NKS + ks; elem = li*8+e
  const int q = tid >> 6, li = tid & 63, fr = li & 15, fq = li >> 4;
  const int cl = 4 * fr + q;
  union { bf16 b8[8]; s16x8 s; } hh, ll;
#pragma unroll
  for (int e = 0; e < 8; e++) split_bf16(tile[fq * 8 + e][cl], hh.b8[e], ll.b8[e]);
  const size_t frag = (size_t)((colblock * 4 + q) * NKS_ + ks);
  *(s16x8*)(Th + frag * 512 + li * 8) = hh.s;
  *(s16x8*)(Tl + frag * 512 + li * 8) = ll.s;
}

// ---------------------------------------------------------------------------
// Fused layer kernel: one block (512 thr, 8 waves) per graph.
// EXACTLY TWO instantiations (<64,true>, <256,false>) -- a third regressed
// graph-warm perf by +50% with identical rocprof counters (R14 bisect).
// h_out==nullptr (runtime, wave-uniform) skips the p5 store (layer 3).
// ---------------------------------------------------------------------------
#define VSTR 260
#define RSTR 260
template <int K, bool FIRST>   // <64,true> (layer1) or <256,false> (layers 2/3)
__global__ __launch_bounds__(512, 4) void k_fused(const float* __restrict__ fin,
                                                  const float* __restrict__ st,
                                                  const bf16* __restrict__ BTh,
                                                  const bf16* __restrict__ BTl,
                                                  const float* __restrict__ bias,
                                                  float* __restrict__ h_out,
                                                  float* __restrict__ part) {
  constexpr int XBYTES = 48 * K * 2 * 2;            // Xh+Xl
  constexpr int ALIAS = (NN * VSTR + 8 * RSTR) * 4; // vsh + red
  constexpr int SBASE = (XBYTES > ALIAS) ? XBYTES : ((ALIAS + 15) & ~15);
  __shared__ __align__(16) char smem[SBASE + 6240 + 160 + 1568];
  bf16* Xh = (bf16*)smem;                  // [48][K]
  bf16* Xl = Xh + 48 * K;                  // [48][K]
  float* vsh = (float*)smem;               // [39][VSTR]  (phase>=4, X dead)
  float* red = (float*)(smem + NN * VSTR * 4);      // [8][RSTR] (phase 5)
  float* dmat = (float*)(smem + SBASE);    // [39][40]
  float* sqv  = (float*)(smem + SBASE + 6240);      // [39]
  int*   idxs = (int*)(smem + SBASE + 6240 + 160);  // [39][10]

  const int b = blockIdx.x, tid = threadIdx.x;
  const int wv = tid >> 6, ln = tid & 63;
  const int fr = ln & 15, fq = ln >> 4;
  const size_t base = (size_t)b * NN;
  constexpr int NKS = K / 32;

  // ---- p0: pipelined load + (BN+relu) + split + swizzled ds_write_b128 ----
  if (FIRST) {
    if (tid < 48 * 8) {
      const int row = tid >> 3, g = tid & 7;
      union { bf16 b8[8]; s16x8 v; } ph, pl;
      if (row < NN) {
#pragma unroll
        for (int j = 0; j < 8; j++) {
          const int k = g * 8 + j;
          const float x = (k < FIN0) ? fin[(base + row) * FIN0 + k] : 0.f;
          split_bf16(x, ph.b8[j], pl.b8[j]);
        }
      } else {
#pragma unroll
        for (int j = 0; j < 8; j++) { ph.b8[j] = __float2bfloat16(0.f); pl.b8[j] = ph.b8[j]; }
      }
      const int ad = row * K + ((g ^ (row & 7)) << 3);
      *(s16x8*)&Xh[ad] = ph.v;
      *(s16x8*)&Xl[ad] = pl.v;
    }
  } else {
    // K=256: exactly 3 granule16/thread (rows r0, r0+16, r0+32), same g.
    const int r0 = tid >> 5, g = tid & 31;
    const unsigned o0 = (unsigned)((((base + r0) * HID) + g * 8) * 4);
    const unsigned rstep = (unsigned)(16 * HID * 4);
    f32x4 a0, a1, b0, b1, c0v, c1v;
    ld_f32x4(a0, fin, o0);             ld_f32x4(a1, fin, o0 + 16);
    ld_f32x4(b0, fin, o0 + rstep);     ld_f32x4(b1, fin, o0 + rstep + 16);
    ld_f32x4(c0v, fin, o0 + 2 * rstep); ld_f32x4(c1v, fin, o0 + 2 * rstep + 16);
    // BN scale/shift for this thread's 8 channels (same for all 3 rows)
    const f32x4 sc0 = *(const f32x4*)&st[g * 8];
    const f32x4 sc1 = *(const f32x4*)&st[g * 8 + 4];
    const f32x4 sh0 = *(const f32x4*)&st[HID + g * 8];
    const f32x4 sh1 = *(const f32x4*)&st[HID + g * 8 + 4];
    WAITV0;
    auto proc = [&](int row, const f32x4& lo4, const f32x4& hi4) {
      union { bf16 b8[8]; s16x8 v; } ph, pl;
#pragma unroll
      for (int j = 0; j < 4; j++) {
        const float v = fmaxf(lo4[j] * sc0[j] + sh0[j], 0.f);
        split_bf16(v, ph.b8[j], pl.b8[j]);
      }
#pragma unroll
      for (int j = 0; j < 4; j++) {
        const float v = fmaxf(hi4[j] * sc1[j] + sh1[j], 0.f);
        split_bf16(v, ph.b8[4 + j], pl.b8[4 + j]);
      }
      const int ad = row * K + ((g ^ (row & 7)) << 3);
      *(s16x8*)&Xh[ad] = ph.v;
      *(s16x8*)&Xl[ad] = pl.v;
    };
    proc(r0, a0, a1);
    proc(r0 + 16, b0, b1);
    const int r2 = r0 + 32;
    if (r2 < NN) proc(r2, c0v, c1v);
    else {                              // pad rows 39..47: zeros
      union { bf16 b8[8]; s16x8 v; } z;
#pragma unroll
      for (int j = 0; j < 8; j++) z.b8[j] = __float2bfloat16(0.f);
      const int ad = r2 * K + ((g ^ (r2 & 7)) << 3);
      *(s16x8*)&Xh[ad] = z.v;
      *(s16x8*)&Xl[ad] = z.v;
    }
  }

  // pre-issue p4's B H(0) fragment loads; the barrier's vmcnt drain lands them
  unsigned fb[4];
#pragma unroll
  for (int n = 0; n < 4; n++)
    fb[n] = ((unsigned)((wv * 4 + n) * NKS) << 10) + (unsigned)(ln * 16);
  s16x8 bufH[4], bufL[4];
#pragma unroll
  for (int n = 0; n < 4; n++) ld_b128(bufH[n], BTh, fb[n]);
  __syncthreads();

  // ---- p1: Gram via MFMA (9 16x16 tile-pairs over 8 waves) ----
  for (int p = wv; p < 9; p += 8) {
    const int mi = p / 3, ni = p % 3;
    f32x4 acg = (f32x4){0.f, 0.f, 0.f, 0.f};
    const int ar = mi * 16 + fr, br = ni * 16 + fr;
#pragma unroll
    for (int ks = 0; ks < NKS; ks++) {
      const int ga = ((ks * 4 + fq) ^ (ar & 7)) << 3;
      const int gb = ((ks * 4 + fq) ^ (br & 7)) << 3;
      const s16x8 avh = *(const s16x8*)&Xh[ar * K + ga];
      const s16x8 avl = *(const s16x8*)&Xl[ar * K + ga];
      const s16x8 bvh = *(const s16x8*)&Xh[br * K + gb];
      const s16x8 bvl = *(const s16x8*)&Xl[br * K + gb];
      acg = __builtin_amdgcn_mfma_f32_16x16x32_bf16(avh, bvh, acg, 0, 0, 0);
      acg = __builtin_amdgcn_mfma_f32_16x16x32_bf16(avh, bvl, acg, 0, 0, 0);
      acg = __builtin_amdgcn_mfma_f32_16x16x32_bf16(avl, bvh, acg, 0, 0, 0);
    }
    const int oc = ni * 16 + fr;           // C layout: col=lane&15
    if (oc < NN) {
#pragma unroll
      for (int r = 0; r < 4; r++) {        // row=(lane>>4)*4+reg
        const int orow = mi * 16 + fq * 4 + r;
        if (orow < NN) dmat[orow * 40 + oc] = acg[r];
      }
    }
  }
  __syncthreads();

  // ---- p2: distances in place ----
  if (tid < NN) sqv[tid] = dmat[tid * 40 + tid];
  __syncthreads();
  for (int t = tid; t < NN * NN; t += 512) {
    const int i = t / NN, j = t - i * NN;
    dmat[i * 40 + j] = sqv[i] + sqv[j] - 2.f * dmat[i * 40 + j];
  }
  __syncthreads();

  // ---- p3: top-10 per row, 4-lane groups (stable tie-break = lax.top_k) ----
  const int grp = tid >> 2, l4 = tid & 3;
  if (grp < NN) {
    float dv[10];
#pragma unroll
    for (int s = 0; s < 10; s++) {
      const int j = l4 + s * 4;
      dv[s] = (j < NN) ? dmat[grp * 40 + j] : 3.4e38f;
    }
    unsigned taken = 0;
    for (int k = 0; k < KNN; k++) {
      float bv = 3.4e38f;
      int bi = 1 << 30;
#pragma unroll
      for (int s = 0; s < 10; s++) {
        const float v = ((taken >> s) & 1u) ? 3.4e38f : dv[s];
        const int j = l4 + s * 4;
        if (v < bv || (v == bv && j < bi)) { bv = v; bi = j; }
      }
#pragma unroll
      for (int m = 1; m < 4; m <<= 1) {
        const float ov = __shfl_xor(bv, m, 64);
        const int oi = __shfl_xor(bi, m, 64);
        if (ov < bv || (ov == bv && oi < bi)) { bv = ov; bi = oi; }
      }
      if ((bi & 3) == l4) taken |= 1u << (bi >> 2);
      if (l4 == 0) idxs[grp * 10 + k] = bi;
    }
  }

  // ---- p4: GEMM. wave wv owns cols [wv*64, wv*64+64); frag n = channels
  //      wcol0 + 4*fr + n. H(0) already resident (pre-barrier issue). ----
  f32x4 acc[3][4];
#pragma unroll
  for (int m = 0; m < 3; m++)
#pragma unroll
    for (int n = 0; n < 4; n++) acc[m][n] = (f32x4){0.f, 0.f, 0.f, 0.f};

#pragma unroll
  for (int ks = 0; ks < NKS; ks++) {
#pragma unroll
    for (int n = 0; n < 4; n++) ld_b128(bufL[n], BTl, fb[n] + (unsigned)ks * 1024);
    s16x8 ah0, ah1, ah2, al0, al1, al2;   // A-fragments once per ks
    {
      const int r0w = fr, r1w = 16 + fr, r2w = 32 + fr;
      const int g0 = ((ks * 4 + fq) ^ (r0w & 7)) << 3;
      const int g1 = ((ks * 4 + fq) ^ (r1w & 7)) << 3;
      const int g2 = ((ks * 4 + fq) ^ (r2w & 7)) << 3;
      ah0 = *(const s16x8*)&Xh[r0w * K + g0]; al0 = *(const s16x8*)&Xl[r0w * K + g0];
      ah1 = *(const s16x8*)&Xh[r1w * K + g1]; al1 = *(const s16x8*)&Xl[r1w * K + g1];
      ah2 = *(const s16x8*)&Xh[r2w * K + g2]; al2 = *(const s16x8*)&Xl[r2w * K + g2];
    }
    WAITV4;                          // H(ks) landed; L(ks) in flight
#pragma unroll
    for (int n = 0; n < 4; n++) {    // hh + lh products (24 MFMA)
      acc[0][n] = __builtin_amdgcn_mfma_f32_16x16x32_bf16(ah0, bufH[n], acc[0][n], 0, 0, 0);
      acc[0][n] = __builtin_amdgcn_mfma_f32_16x16x32_bf16(al0, bufH[n], acc[0][n], 0, 0, 0);
      acc[1][n] = __builtin_amdgcn_mfma_f32_16x16x32_bf16(ah1, bufH[n], acc[1][n], 0, 0, 0);
      acc[1][n] = __builtin_amdgcn_mfma_f32_16x16x32_bf16(al1, bufH[n], acc[1][n], 0, 0, 0);
      acc[2][n] = __builtin_amdgcn_mfma_f32_16x16x32_bf16(ah2, bufH[n], acc[2][n], 0, 0, 0);
      acc[2][n] = __builtin_amdgcn_mfma_f32_16x16x32_bf16(al2, bufH[n], acc[2][n], 0, 0, 0);
    }
    if (ks + 1 < NKS) {
#pragma unroll
      for (int n = 0; n < 4; n++) ld_b128(bufH[n], BTh, fb[n] + (unsigned)(ks + 1) * 1024);
      WAITV4;                        // L(ks) landed; H(ks+1) in flight
    } else {
      WAITV0;                        // L(last) landed
    }
#pragma unroll
    for (int n = 0; n < 4; n++) {    // hl products (12 MFMA)
      acc[0][n] = __builtin_amdgcn_mfma_f32_16x16x32_bf16(ah0, bufL[n], acc[0][n], 0, 0, 0);
      acc[1][n] = __builtin_amdgcn_mfma_f32_16x16x32_bf16(ah1, bufL[n], acc[1][n], 0, 0, 0);
      acc[2][n] = __builtin_amdgcn_mfma_f32_16x16x32_bf16(ah2, bufL[n], acc[2][n], 0, 0, 0);
    }
  }
  __syncthreads();   // all X-reads done; X region may be overwritten (vsh)

  if (wv >= 4) {     // v-waves: acc -> vsh[row][c0..c0+3] (f32x4 stores)
    const int c0 = (wv - 4) * 64 + fr * 4;
#pragma unroll
    for (int m = 0; m < 3; m++)
#pragma unroll
      for (int r = 0; r < 4; r++) {
        const int row = m * 16 + fq * 4 + r;
        if (row < NN) {
          const f32x4 v4 = (f32x4){acc[m][0][r], acc[m][1][r], acc[m][2][r], acc[m][3][r]};
          *(f32x4*)&vsh[row * VSTR + c0] = v4;
        }
      }
  } else {           // u-waves: add bias (channel c0+n per acc slot n)
    const int c0 = wv * 64 + fr * 4;
    const f32x4 bv = *(const f32x4*)&bias[c0];
#pragma unroll
    for (int n = 0; n < 4; n++)
#pragma unroll
      for (int m = 0; m < 3; m++)
#pragma unroll
        for (int r = 0; r < 4; r++) acc[m][n][r] += bv[n];
  }
  __syncthreads();   // vsh + idxs ready

  // ---- p5: h = relu(u + max_k v); f32x4 LDS reads; BN partials ----
  if (wv < 4) {
    const bool wh = (h_out != nullptr);   // wave-uniform; layer 3 skips store
    const int c0 = wv * 64 + fr * 4;
    f32x4 s1 = (f32x4){0.f, 0.f, 0.f, 0.f}, s2 = (f32x4){0.f, 0.f, 0.f, 0.f};
#pragma unroll
    for (int m = 0; m < 3; m++)
#pragma unroll
      for (int r = 0; r < 4; r++) {
        const int row = m * 16 + fq * 4 + r;
        if (row < NN) {
          int nb[10];
#pragma unroll
          for (int k = 0; k < KNN; k++) nb[k] = idxs[row * 10 + k];
          f32x4 vm = (f32x4){-3.4e38f, -3.4e38f, -3.4e38f, -3.4e38f};
#pragma unroll
          for (int k = 0; k < KNN; k++) {
            const f32x4 t4 = *(const f32x4*)&vsh[nb[k] * VSTR + c0];
            vm[0] = fmaxf(vm[0], t4[0]); vm[1] = fmaxf(vm[1], t4[1]);
            vm[2] = fmaxf(vm[2], t4[2]); vm[3] = fmaxf(vm[3], t4[3]);
          }
          f32x4 h4;
#pragma unroll
          for (int j = 0; j < 4; j++) h4[j] = fmaxf(acc[m][j][r] + vm[j], 0.f);
          if (wh) *(f32x4*)&h_out[(size_t)(base + row) * HID + c0] = h4;
#pragma unroll
          for (int j = 0; j < 4; j++) { s1[j] += h4[j]; s2[j] += h4[j] * h4[j]; }
        }
      }
    *(f32x4*)&red[fq * RSTR + c0] = s1;
    *(f32x4*)&red[(4 + fq) * RSTR + c0] = s2;
  }
  __syncthreads();
  if (tid < HID) {
    part[(size_t)b * 512 + tid] =
        red[0 * RSTR + tid] + red[1 * RSTR + tid] + red[2 * RSTR + tid] + red[3 * RSTR + tid];
    part[(size_t)b * 512 + HID + tid] =
        red[4 * RSTR + tid] + red[5 * RSTR + tid] + red[6 * RSTR + tid] + red[7 * RSTR + tid];
  }
}

// stats reduce: one block per channel; deterministic tree order.
__global__ __launch_bounds__(256) void k_stats(const float* __restrict__ part,
                                               const float* __restrict__ gam,
                                               const float* __restrict__ bet,
                                               float* __restrict__ st) {
  __shared__ float rs[4], rq[4];
  const int c = blockIdx.x, tid = threadIdx.x;
  float s = part[(size_t)tid * 512 + c] + part[(size_t)(tid + 256) * 512 + c];
  float q = part[(size_t)tid * 512 + HID + c] + part[(size_t)(tid + 256) * 512 + HID + c];
#pragma unroll
  for (int m = 32; m >= 1; m >>= 1) { s += __shfl_down(s, m, 64); q += __shfl_down(q, m, 64); }
  if ((tid & 63) == 0) { rs[tid >> 6] = s; rq[tid >> 6] = q; }
  __syncthreads();
  if (tid == 0) {
    s = rs[0] + rs[1] + rs[2] + rs[3];
    q = rq[0] + rq[1] + rq[2] + rq[3];
    const float mean = s * (1.f / NROWS);
    const float var = q * (1.f / NROWS) - mean * mean;
    const float sc = gam[c] * rsqrtf(var + BNEPS);
    st[c] = sc;
    st[HID + c] = bet[c] - mean * sc;
  }
}

// final: pooled = BN(part_sum/NN); logits; softmax.  part[b*512+c] is the
// channel-sum of h3 over graph b's 39 rows (computed by layer-3's p5).
__global__ __launch_bounds__(256) void k_final(const float* __restrict__ part,
                                               const float* __restrict__ st,
                                               const float* __restrict__ Wl,
                                               const float* __restrict__ bl,
                                               float* __restrict__ out) {
  __shared__ float r0[HID], r1[HID];
  const int b = blockIdx.x, c = threadIdx.x;
  const float s = part[(size_t)b * 512 + c];
  const float pooled = (s * (1.f / NN)) * st[c] + st[HID + c];
  r0[c] = pooled * Wl[c * 2 + 0];
  r1[c] = pooled * Wl[c * 2 + 1];
  __syncthreads();
  for (int stp = 128; stp > 0; stp >>= 1) {
    if (c < stp) { r0[c] += r0[c + stp]; r1[c] += r1[c + stp]; }
    __syncthreads();
  }
  if (c == 0) {
    const float l0 = r0[0] + bl[0], l1 = r1[0] + bl[1];
    const float mx = fmaxf(l0, l1);
    const float e0 = expf(l0 - mx), e1 = expf(l1 - mx);
    const float inv = 1.f / (e0 + e1);
    out[b * 2 + 0] = e0 * inv;
    out[b * 2 + 1] = e1 * inv;
  }
}

extern "C" void kernel_launch(void* const* d_in, const int* in_sizes, int n_in,
                              void* d_out, int out_size, void* d_ws, size_t ws_size,
                              hipStream_t stream) {
  const float* x   = (const float*)d_in[0];
  // d_in[1] = batch (structure fixed: repeat(arange(512), 39)) -- unused
  const float* W1  = (const float*)d_in[2];
  const float* b1  = (const float*)d_in[3];
  const float* W2  = (const float*)d_in[4];
  const float* b2  = (const float*)d_in[5];
  const float* W3  = (const float*)d_in[6];
  const float* b3  = (const float*)d_in[7];
  const float* g1  = (const float*)d_in[8];
  const float* be1 = (const float*)d_in[9];
  const float* g2  = (const float*)d_in[10];
  const float* be2 = (const float*)d_in[11];
  const float* g3  = (const float*)d_in[12];
  const float* be3 = (const float*)d_in[13];
  const float* Wl  = (const float*)d_in[14];
  const float* bl  = (const float*)d_in[15];

  char* ws = (char*)d_ws;
  size_t off = 0;
  auto alloc = [&](size_t bytes) {
    size_t o = off;
    off += (bytes + 255) & ~(size_t)255;
    return o;
  };
  bf16* W1Th = (bf16*)(ws + alloc(512 * 64 * 2));
  bf16* W1Tl = (bf16*)(ws + alloc(512 * 64 * 2));
  bf16* W2Th = (bf16*)(ws + alloc(512 * 256 * 2));
  bf16* W2Tl = (bf16*)(ws + alloc(512 * 256 * 2));
  bf16* W3Th = (bf16*)(ws + alloc(512 * 256 * 2));
  bf16* W3Tl = (bf16*)(ws + alloc(512 * 256 * 2));
  float* hA  = (float*)(ws + alloc((size_t)NROWS * HID * 4));
  float* hB  = (float*)(ws + alloc((size_t)NROWS * HID * 4));
  float* part = (float*)(ws + alloc((size_t)NG * 512 * 4));
  float* st1 = (float*)(ws + alloc(512 * 4));
  float* st2 = (float*)(ws + alloc(512 * 4));
  float* st3 = (float*)(ws + alloc(512 * 4));
  if (off > ws_size) return;  // workspace too small -> visible failure

  k_prepw<<<144, 256, 0, stream>>>(W1, W2, W3, W1Th, W1Tl, W2Th, W2Tl, W3Th, W3Tl);

  // layer 1 (raw x input, no BN on load)
  k_fused<64, true><<<NG, 512, 0, stream>>>(x, nullptr, W1Th, W1Tl, b1, hA, part);
  k_stats<<<HID, 256, 0, stream>>>(part, g1, be1, st1);

  // layer 2 (BN+relu of hA applied on load)
  k_fused<256, false><<<NG, 512, 0, stream>>>(hA, st1, W2Th, W2Tl, b2, hB, part);
  k_stats<<<HID, 256, 0, stream>>>(part, g2, be2, st2);

  // layer 3 (h3 store skipped via runtime null h_out; same instantiation)
  k_fused<256, false><<<NG, 512, 0, stream>>>(hB, st2, W3Th, W3Tl, b3, nullptr, part);
  k_stats<<<HID, 256, 0, stream>>>(part, g3, be3, st3);

  // pool (from part, 1 MB) + linear + softmax
  k_final<<<NG, 256, 0, stream>>>(part, st3, Wl, bl, (float*)d_out);
}